// Round 1
// 320.959 us; speedup vs baseline: 1.0607x; 1.0607x over previous
//
#include <hip/hip_runtime.h>

// GCN: 2-layer GraphConv, N=100000, E=1600000, 128 -> 128 -> 40 (fp32).
// Round 10: latency-batched gathers.
//   gather1: predicated 16-edge batches (no serial remainder loop), uint4 row
//            reads (16 lanes/row, 4 rows per load instr), 2 mem round trips
//            per 16 edges for ANY degree.
//   gather2: predicated 18-edge batches (3 loads/lane in flight).
// Rest of pipeline unchanged from Round 9 (dual counting-sort CSR build).
constexpr int NN   = 100000;
constexpr int NE   = 1600000;
constexpr int INF  = 128;
constexpr int NC   = 40;

constexpr int BKSH = 9;                        // 512 nodes per coarse bucket
constexpr int NBK  = (NN + 511) / 512;         // 196 buckets
constexpr int EPB  = 4096;                     // edges per partition block
constexpr int PBLK = (NE + EPB - 1) / EPB;     // 391
constexpr int CAP  = 14336;                    // pass2 LDS esrc capacity (56 KB)
constexpr int HB   = 391;                      // hist blocks in merged kernel

typedef __attribute__((ext_vector_type(8))) short short8;
typedef __attribute__((ext_vector_type(4))) float f32x4;

__device__ __forceinline__ float bflo(unsigned int u) { return __uint_as_float(u << 16); }
__device__ __forceinline__ float bfhi(unsigned int u) { return __uint_as_float(u & 0xffff0000u); }
__device__ __forceinline__ unsigned short f2bf(float f) {          // RNE
    unsigned int u = __float_as_uint(f);
    return (unsigned short)((u + 0x7fffu + ((u >> 16) & 1u)) >> 16);
}
__device__ __forceinline__ unsigned int pack2(float a, float b) {
    return (unsigned int)f2bf(a) | ((unsigned int)f2bf(b) << 16);
}

// blocks 0..HB-1: coarse dst-bucket AND src-bucket histograms (LDS aggregated).
// blocks HB..HB+6249: x (fp32) -> xh (bf16). +2 blocks: W1/W2 transpose->bf16.
__global__ __launch_bounds__(256) void histconv_kernel(const int* __restrict__ src,
                                                       const int* __restrict__ dst,
                                                       unsigned int* __restrict__ bcntD,
                                                       unsigned int* __restrict__ bcntS,
                                                       const float* __restrict__ x,
                                                       const float* __restrict__ W1,
                                                       const float* __restrict__ W2,
                                                       unsigned short* __restrict__ xh,
                                                       unsigned short* __restrict__ w1t,
                                                       unsigned short* __restrict__ w2t) {
    const int b = blockIdx.x;
    const int tid = threadIdx.x;
    if (b < HB) {
        __shared__ unsigned int hcD[NBK];
        __shared__ unsigned int hcS[NBK];
        for (int i = tid; i < NBK; i += 256) { hcD[i] = 0u; hcS[i] = 0u; }
        __syncthreads();
        int gid = b * 256 + tid;
        int stride = HB * 256;
        for (int e = gid; e < NE; e += stride) {
            atomicAdd(&hcD[dst[e] >> BKSH], 1u);
            atomicAdd(&hcS[src[e] >> BKSH], 1u);
        }
        __syncthreads();
        for (int i = tid; i < NBK; i += 256) {
            if (hcD[i]) atomicAdd(&bcntD[i], hcD[i]);
            if (hcS[i]) atomicAdd(&bcntS[i], hcS[i]);
        }
    } else if (b < HB + 6250) {
        int j = (b - HB) * 256 + tid;                // uint4 index, N*128/8 = 1.6M
        float4 v0 = ((const float4*)x)[2 * j];
        float4 v1 = ((const float4*)x)[2 * j + 1];
        uint4 o;
        o.x = pack2(v0.x, v0.y);
        o.y = pack2(v0.z, v0.w);
        o.z = pack2(v1.x, v1.y);
        o.w = pack2(v1.z, v1.w);
        ((uint4*)xh)[j] = o;
    } else if (b == HB + 6250) {
        for (int i = tid; i < 128 * 128; i += 256) {
            int k = i >> 7, n = i & 127;
            w1t[n * 128 + k] = f2bf(W1[i]);
        }
    } else {
        for (int i = tid; i < 48 * 128; i += 256) {
            int n = i >> 7, k = i & 127;
            w2t[i] = f2bf((n < NC) ? W2[k * NC + n] : 0.f);
        }
    }
}

// dual partition: dst-records (src | dst_local<<17) into epartsD, src-records
// (ushort src_local) into epartsS. Both LDS-staged -> coalesced run dumps.
__global__ __launch_bounds__(256) void partition_kernel(const int* __restrict__ src,
                                                        const int* __restrict__ dst,
                                                        const unsigned int* __restrict__ bcntD,
                                                        const unsigned int* __restrict__ bcntS,
                                                        int* __restrict__ curD_g,
                                                        int* __restrict__ curS_g,
                                                        int* __restrict__ epartsD,
                                                        unsigned short* __restrict__ epartsS) {
    __shared__ int sc[256];
    __shared__ int cntD[NBK], gadjD[NBK], curD[NBK];
    __shared__ int cntS[NBK], gadjS[NBK], curS[NBK];
    __shared__ int baselD[NBK], baselS[NBK];
    __shared__ int stageD[EPB];
    __shared__ unsigned short stageS[EPB];
    __shared__ unsigned char bidD[EPB];
    __shared__ unsigned char bidS[EPB];
    const int tid = threadIdx.x;
    const int e0 = blockIdx.x * EPB;
    const int total = min(EPB, NE - e0);

    // self-scan of global bucket counts -> base offsets (dst then src)
    {
        int v = (tid < NBK) ? (int)bcntD[tid] : 0;
        sc[tid] = v;
        __syncthreads();
        for (int off = 1; off < 256; off <<= 1) {
            int t = (tid >= off) ? sc[tid - off] : 0;
            __syncthreads();
            sc[tid] += t;
            __syncthreads();
        }
        if (tid < NBK) baselD[tid] = sc[tid] - v;
        __syncthreads();
        v = (tid < NBK) ? (int)bcntS[tid] : 0;
        sc[tid] = v;
        __syncthreads();
        for (int off = 1; off < 256; off <<= 1) {
            int t = (tid >= off) ? sc[tid - off] : 0;
            __syncthreads();
            sc[tid] += t;
            __syncthreads();
        }
        if (tid < NBK) baselS[tid] = sc[tid] - v;
    }
    for (int i = tid; i < NBK; i += 256) { cntD[i] = 0; cntS[i] = 0; }
    __syncthreads();
    // phase A: count per bucket (both keys)
    for (int i = tid; i < total; i += 256) {
        atomicAdd(&cntD[dst[e0 + i] >> BKSH], 1);
        atomicAdd(&cntS[src[e0 + i] >> BKSH], 1);
    }
    __syncthreads();
    // exclusive scans of cntD, cntS; reserve global ranges
    {
        int v = (tid < NBK) ? cntD[tid] : 0;
        sc[tid] = v;
        __syncthreads();
        for (int off = 1; off < 256; off <<= 1) {
            int t = (tid >= off) ? sc[tid - off] : 0;
            __syncthreads();
            sc[tid] += t;
            __syncthreads();
        }
        if (tid < NBK) {
            int excl = sc[tid] - v;
            curD[tid] = excl;
            int g = (v > 0) ? atomicAdd(&curD_g[tid], v) : 0;   // zero-based
            gadjD[tid] = baselD[tid] + g - excl;
        }
        __syncthreads();
        v = (tid < NBK) ? cntS[tid] : 0;
        sc[tid] = v;
        __syncthreads();
        for (int off = 1; off < 256; off <<= 1) {
            int t = (tid >= off) ? sc[tid - off] : 0;
            __syncthreads();
            sc[tid] += t;
            __syncthreads();
        }
        if (tid < NBK) {
            int excl = sc[tid] - v;
            curS[tid] = excl;
            int g = (v > 0) ? atomicAdd(&curS_g[tid], v) : 0;
            gadjS[tid] = baselS[tid] + g - excl;
        }
    }
    __syncthreads();
    // phase B: re-read edges, stage grouped by bucket (both keys)
    for (int i = tid; i < total; i += 256) {
        int s = src[e0 + i];
        int d = dst[e0 + i];
        int bD = d >> BKSH;
        int offD = atomicAdd(&curD[bD], 1);
        stageD[offD] = s | ((d - (bD << BKSH)) << 17);
        bidD[offD] = (unsigned char)bD;
        int bS = s >> BKSH;
        int offS = atomicAdd(&curS[bS], 1);
        stageS[offS] = (unsigned short)(s - (bS << BKSH));
        bidS[offS] = (unsigned char)bS;
    }
    __syncthreads();
    // dumps: consecutive j within a bucket-run -> consecutive global addresses
    for (int j = tid; j < total; j += 256) {
        int b = bidD[j];
        epartsD[gadjD[b] + j] = stageD[j];
    }
    for (int j = tid; j < total; j += 256) {
        int b = bidS[j];
        epartsS[gadjS[b] + j] = stageS[j];
    }
}

// per-bucket: dst CSR (hist+scan+LDS scatter -> row_ptr, dstn, esrc) AND
// src out-degree hist -> srcn. All histograms in LDS.
__global__ __launch_bounds__(512) void pass2_kernel(const int* __restrict__ epartsD,
                                                    const unsigned short* __restrict__ epartsS,
                                                    const unsigned int* __restrict__ bcntD,
                                                    const unsigned int* __restrict__ bcntS,
                                                    int* __restrict__ row_ptr,
                                                    int* __restrict__ esrc,
                                                    float* __restrict__ srcn,
                                                    float* __restrict__ dstn) {
    __shared__ int hist[512];
    __shared__ int cur[512];
    __shared__ int histS[512];
    __shared__ int lesrc[CAP];
    __shared__ int base_s, cnt_s, baseS_s, cntS_s;
    const int tid = threadIdx.x;
    const int b = blockIdx.x;

    // self-scans of bucket counts -> this bucket's base/cnt (dst, then src)
    {
        int v = (tid < NBK) ? (int)bcntD[tid] : 0;
        hist[tid] = v;
        __syncthreads();
        for (int off = 1; off < 512; off <<= 1) {
            int t = (tid >= off) ? hist[tid - off] : 0;
            __syncthreads();
            hist[tid] += t;
            __syncthreads();
        }
        if (tid == b) { base_s = hist[b] - v; cnt_s = v; }
        __syncthreads();
        v = (tid < NBK) ? (int)bcntS[tid] : 0;
        hist[tid] = v;
        __syncthreads();
        for (int off = 1; off < 512; off <<= 1) {
            int t = (tid >= off) ? hist[tid - off] : 0;
            __syncthreads();
            hist[tid] += t;
            __syncthreads();
        }
        if (tid == b) { baseS_s = hist[b] - v; cntS_s = v; }
        __syncthreads();
    }
    const int base = base_s;
    const int cnt = cnt_s;
    const int baseS = baseS_s;
    const int cntS = cntS_s;
    const int n0 = b << BKSH;
    const int nloc = min(512, NN - n0);

    hist[tid] = 0;
    histS[tid] = 0;
    __syncthreads();
    for (int j = tid; j < cnt; j += 512)
        atomicAdd(&hist[epartsD[base + j] >> 17], 1);
    for (int j = tid; j < cntS; j += 512)
        atomicAdd(&histS[(int)epartsS[baseS + j]], 1);
    __syncthreads();
    int myc = hist[tid];
    int mycS = histS[tid];
    for (int off = 1; off < 512; off <<= 1) {
        int t = (tid >= off) ? hist[tid - off] : 0;
        __syncthreads();
        hist[tid] += t;
        __syncthreads();
    }
    int excl = hist[tid] - myc;
    cur[tid] = excl;
    if (tid < nloc) {
        int g = n0 + tid;
        row_ptr[g] = base + excl;
        dstn[g] = rsqrtf(fmaxf((float)myc, 1.0f));    // dst_norm (in-degree)
        srcn[g] = rsqrtf(fmaxf((float)mycS, 1.0f));   // src_norm (out-degree)
    }
    if (b == NBK - 1 && tid == 0) row_ptr[NN] = NE;
    __syncthreads();
    if (cnt <= CAP) {
        for (int j = tid; j < cnt; j += 512) {
            int rec = epartsD[base + j];
            int pos = atomicAdd(&cur[rec >> 17], 1);
            lesrc[pos] = rec & 0x1FFFF;
        }
        __syncthreads();
        for (int j = tid; j < cnt; j += 512) esrc[base + j] = lesrc[j];
    } else {
        for (int j = tid; j < cnt; j += 512) {
            int rec = epartsD[base + j];
            int pos = atomicAdd(&cur[rec >> 17], 1);
            esrc[base + pos] = rec & 0x1FFFF;
        }
    }
}

// one wave per node: aggb[node] = bf16( sum x_bf16[esrc[e]] * src_norm[esrc[e]] )
// Round 10: predicated 16-edge batches. lane = quad*16+l16; quad group t*4+quad
// owns edge slot, l16 indexes 16B (uint4 = 8 bf16) within the 256 B row.
// Out-of-range slots clamp to edge `beg` (row is L1/L2-hot) with norm = 0.
// Every node completes in ceil(deg/16) iterations of ~2 memory round trips.
__global__ __launch_bounds__(256) void gather1_kernel(const int* __restrict__ row_ptr,
                                                      const int* __restrict__ esrc,
                                                      const unsigned short* __restrict__ xh,
                                                      const float* __restrict__ src_norm,
                                                      unsigned short* __restrict__ aggb) {
    int node = (blockIdx.x * blockDim.x + threadIdx.x) >> 6;
    int lane = threadIdx.x & 63;
    if (node >= NN) return;
    int beg = __builtin_amdgcn_readfirstlane(row_ptr[node]);
    int end = __builtin_amdgcn_readfirstlane(row_ptr[node + 1]);
    const int quad = lane >> 4;       // edge-slot group 0..3
    const int l16  = lane & 15;       // uint4 index within 256 B row
    float acc0 = 0.f, acc1 = 0.f, acc2 = 0.f, acc3 = 0.f;
    float acc4 = 0.f, acc5 = 0.f, acc6 = 0.f, acc7 = 0.f;
    for (int e = beg; e < end; e += 16) {
        const int rem = end - e;
        int s[4];
#pragma unroll
        for (int t = 0; t < 4; ++t) {
            int slot = t * 4 + quad;
            int idx = (slot < rem) ? (e + slot) : beg;
            s[t] = esrc[idx];
        }
        float n[4];
        uint4 u[4];
#pragma unroll
        for (int t = 0; t < 4; ++t) {
            int slot = t * 4 + quad;
            n[t] = (slot < rem) ? src_norm[s[t]] : 0.f;
            u[t] = ((const uint4*)(xh + (size_t)s[t] * INF))[l16];
        }
#pragma unroll
        for (int t = 0; t < 4; ++t) {
            acc0 += bflo(u[t].x) * n[t];
            acc1 += bfhi(u[t].x) * n[t];
            acc2 += bflo(u[t].y) * n[t];
            acc3 += bfhi(u[t].y) * n[t];
            acc4 += bflo(u[t].z) * n[t];
            acc5 += bfhi(u[t].z) * n[t];
            acc6 += bflo(u[t].w) * n[t];
            acc7 += bfhi(u[t].w) * n[t];
        }
    }
    // reduce across the 4 quad groups (same l16): lanes l16 <- l16 + {16,32,48}
    acc0 += __shfl_down(acc0, 32); acc1 += __shfl_down(acc1, 32);
    acc2 += __shfl_down(acc2, 32); acc3 += __shfl_down(acc3, 32);
    acc4 += __shfl_down(acc4, 32); acc5 += __shfl_down(acc5, 32);
    acc6 += __shfl_down(acc6, 32); acc7 += __shfl_down(acc7, 32);
    acc0 += __shfl_down(acc0, 16); acc1 += __shfl_down(acc1, 16);
    acc2 += __shfl_down(acc2, 16); acc3 += __shfl_down(acc3, 16);
    acc4 += __shfl_down(acc4, 16); acc5 += __shfl_down(acc5, 16);
    acc6 += __shfl_down(acc6, 16); acc7 += __shfl_down(acc7, 16);
    if (lane < 16) {
        uint4 o;
        o.x = pack2(acc0, acc1);
        o.y = pack2(acc2, acc3);
        o.z = pack2(acc4, acc5);
        o.w = pack2(acc6, acc7);
        ((uint4*)(aggb + (size_t)node * INF))[l16] = o;
    }
}

// Fused GEMM1+GEMM2 via MFMA 16x16x32 bf16. 64 rows/block, 4 waves, wave-private rows.
// h = relu(dstn*(agg@W1) + b1) into LDS (bf16), then out = (h@W2)*srcn -> hwb.
__global__ __launch_bounds__(256) void gemm12_kernel(const unsigned short* __restrict__ aggb,
                                                     const unsigned short* __restrict__ w1t,
                                                     const unsigned short* __restrict__ w2t,
                                                     const float* __restrict__ b1,
                                                     const float* __restrict__ dstn,
                                                     const float* __restrict__ srcn,
                                                     unsigned short* __restrict__ hwb) {
    __shared__ unsigned short At[64 * 128];    // 16 KB: agg tile, then h tile
    __shared__ unsigned short W1l[128 * 128];  // 32 KB
    __shared__ unsigned short W2l[48 * 128];   // 12 KB
    __shared__ float dn[64], sn[64], b1l[128];
    const int tid = threadIdx.x;
    const int r0 = blockIdx.x * 64;

    {   // stage weights (uint4 = 8 bf16)
        const uint4* g1 = (const uint4*)w1t;
        uint4* s1 = (uint4*)W1l;
        for (int i = tid; i < 2048; i += 256) s1[i] = g1[i];
        const uint4* g2 = (const uint4*)w2t;
        uint4* s2 = (uint4*)W2l;
        for (int i = tid; i < 768; i += 256) s2[i] = g2[i];
    }
    {   // stage agg tile (zero-pad rows >= NN)
        const uint4* g = (const uint4*)(aggb + (size_t)r0 * 128);
        uint4* s = (uint4*)At;
        for (int i = tid; i < 1024; i += 256) {
            int row = i >> 4;
            uint4 v = make_uint4(0, 0, 0, 0);
            if (r0 + row < NN) v = g[i];
            s[i] = v;
        }
    }
    if (tid < 64) {
        int r = r0 + tid;
        dn[tid] = (r < NN) ? dstn[r] : 0.f;
        sn[tid] = (r < NN) ? srcn[r] : 0.f;
    }
    if (tid >= 64 && tid < 192) b1l[tid - 64] = b1[tid - 64];
    __syncthreads();

    const int wv    = tid >> 6;
    const int lane  = tid & 63;
    const int lrow  = lane & 15;
    const int lquad = lane >> 4;

    short8 afrag[4];
#pragma unroll
    for (int ks = 0; ks < 4; ++ks)
        afrag[ks] = *(const short8*)&At[(wv * 16 + lrow) * 128 + ks * 32 + lquad * 8];
    float hreg[8][4];
#pragma unroll
    for (int nt = 0; nt < 8; ++nt) {
        f32x4 acc = {0.f, 0.f, 0.f, 0.f};
#pragma unroll
        for (int ks = 0; ks < 4; ++ks) {
            short8 bfr = *(const short8*)&W1l[(nt * 16 + lrow) * 128 + ks * 32 + lquad * 8];
            acc = __builtin_amdgcn_mfma_f32_16x16x32_bf16(afrag[ks], bfr, acc, 0, 0, 0);
        }
#pragma unroll
        for (int i = 0; i < 4; ++i) hreg[nt][i] = acc[i];
    }
#pragma unroll
    for (int nt = 0; nt < 8; ++nt) {
        int col = nt * 16 + lrow;
        float bb = b1l[col];
#pragma unroll
        for (int i = 0; i < 4; ++i) {
            int row = wv * 16 + lquad * 4 + i;
            At[row * 128 + col] = f2bf(fmaxf(hreg[nt][i] * dn[row] + bb, 0.f));
        }
    }
    __syncthreads();

#pragma unroll
    for (int ks = 0; ks < 4; ++ks)
        afrag[ks] = *(const short8*)&At[(wv * 16 + lrow) * 128 + ks * 32 + lquad * 8];
#pragma unroll
    for (int nt = 0; nt < 3; ++nt) {
        f32x4 acc = {0.f, 0.f, 0.f, 0.f};
#pragma unroll
        for (int ks = 0; ks < 4; ++ks) {
            short8 bfr = *(const short8*)&W2l[(nt * 16 + lrow) * 128 + ks * 32 + lquad * 8];
            acc = __builtin_amdgcn_mfma_f32_16x16x32_bf16(afrag[ks], bfr, acc, 0, 0, 0);
        }
        int col = nt * 16 + lrow;
        if (col < NC) {
#pragma unroll
            for (int i = 0; i < 4; ++i) {
                int row = wv * 16 + lquad * 4 + i;
                int grow = r0 + row;
                if (grow < NN)
                    hwb[(size_t)grow * NC + col] = f2bf(acc[i] * sn[row]);
            }
        }
    }
}

// one wave per node. lane = g*10+j (g<6, j<10): 6 edge slots, each edge's
// 80 B row read by 10 lanes as uint2 (4 bf16). Round 10: predicated 18-edge
// batches (3 independent loads per lane in flight); invalid slots clamp to
// edge `beg` with multiplicative zero mask. fp32 acc; shfl reduce into lanes
// 0..9, which store float4 with fused *dstn + b2.
__global__ __launch_bounds__(256) void gather2_kernel(const int* __restrict__ row_ptr,
                                                      const int* __restrict__ esrc,
                                                      const unsigned short* __restrict__ hwb,
                                                      const float* __restrict__ dst_norm,
                                                      const float* __restrict__ b2,
                                                      float* __restrict__ out) {
    int node = (blockIdx.x * blockDim.x + threadIdx.x) >> 6;
    int lane = threadIdx.x & 63;
    if (node >= NN) return;
    int beg = __builtin_amdgcn_readfirstlane(row_ptr[node]);
    int end = __builtin_amdgcn_readfirstlane(row_ptr[node + 1]);
    const int g = lane / 10;          // edge slot 0..5 (g==6: lanes 60-63 masked)
    const int j = lane - g * 10;      // uint2 index within 80 B row
    const bool active = (g < 6);
    float4 acc = make_float4(0.f, 0.f, 0.f, 0.f);
    for (int e = beg; e < end; e += 18) {
        const int rem = end - e;
        int s[3];
        float m[3];
#pragma unroll
        for (int q = 0; q < 3; ++q) {
            int slot = q * 6 + g;
            bool v = active && (slot < rem);
            int idx = v ? (e + slot) : beg;
            s[q] = esrc[idx];
            m[q] = v ? 1.f : 0.f;
        }
        uint2 u[3];
#pragma unroll
        for (int q = 0; q < 3; ++q)
            u[q] = ((const uint2*)(hwb + (size_t)s[q] * NC))[j];
#pragma unroll
        for (int q = 0; q < 3; ++q) {
            acc.x += bflo(u[q].x) * m[q];
            acc.y += bfhi(u[q].x) * m[q];
            acc.z += bflo(u[q].y) * m[q];
            acc.w += bfhi(u[q].y) * m[q];
        }
    }
    float4 tot = acc;
#pragma unroll
    for (int k = 1; k < 6; ++k) {
        tot.x += __shfl(acc.x, j + 10 * k);
        tot.y += __shfl(acc.y, j + 10 * k);
        tot.z += __shfl(acc.z, j + 10 * k);
        tot.w += __shfl(acc.w, j + 10 * k);
    }
    if (lane < 10) {
        float dnv = dst_norm[node];
        float4 bb = ((const float4*)b2)[j];
        float4 o;
        o.x = tot.x * dnv + bb.x;
        o.y = tot.y * dnv + bb.y;
        o.z = tot.z * dnv + bb.z;
        o.w = tot.w * dnv + bb.w;
        ((float4*)(out + (size_t)node * NC))[j] = o;
    }
}

extern "C" void kernel_launch(void* const* d_in, const int* in_sizes, int n_in,
                              void* d_out, int out_size, void* d_ws, size_t ws_size,
                              hipStream_t stream) {
    const float* x   = (const float*)d_in[0];
    const float* W1  = (const float*)d_in[1];
    const float* b1  = (const float*)d_in[2];
    const float* W2  = (const float*)d_in[3];
    const float* b2  = (const float*)d_in[4];
    const int*   src = (const int*)d_in[5];
    const int*   dst = (const int*)d_in[6];
    float* out = (float*)d_out;

    // workspace (4B units):
    // srcn[NN] | bcntD[256] | bcntS[256] | curD[256] | curS[256] | row_ptr[NN+1] |
    // dstn[NN] | esrc[NE] | pad | aggb[NN*64] | xh[NN*64] | w1t[8192] | w2t[3072]
    // hwb (bf16 NN*40) ALIASES xh (xh dead after gather1, hwb written by gemm12 after).
    float* srcn = (float*)d_ws;
    unsigned int* bcntD = (unsigned int*)(srcn + NN);
    unsigned int* bcntS = bcntD + 256;
    int* curD = (int*)(bcntS + 256);
    int* curS = curD + 256;
    int* row_ptr = curS + 256;
    float* dstn  = (float*)(row_ptr + NN + 1);
    int* esrc    = (int*)(dstn + NN);
    size_t ofs = (size_t)NN + 1024 + (NN + 1) + NN + NE;
    ofs = (ofs + 3) & ~(size_t)3;                 // 16B align
    unsigned short* aggb = (unsigned short*)((float*)d_ws + ofs);
    unsigned short* xh   = aggb + (size_t)NN * INF;
    unsigned short* w1t  = xh + (size_t)NN * INF;
    unsigned short* w2t  = w1t + 128 * 128;
    unsigned short* hwb  = xh;                    // alias — see lifetime note above

    // edge-record scratch lives in d_out (9.6 MB of 16 MB) — dead before gather2 writes
    int* epartsD = (int*)d_out;                            // 6.4 MB
    unsigned short* epartsS = (unsigned short*)(epartsD + NE);  // 3.2 MB

    hipMemsetAsync(bcntD, 0, 1024 * sizeof(int), stream);  // bcntD|bcntS|curD|curS

    histconv_kernel<<<HB + 6252, 256, 0, stream>>>(src, dst, bcntD, bcntS,
                                                   x, W1, W2, xh, w1t, w2t);
    partition_kernel<<<PBLK, 256, 0, stream>>>(src, dst, bcntD, bcntS, curD, curS,
                                               epartsD, epartsS);
    pass2_kernel<<<NBK, 512, 0, stream>>>(epartsD, epartsS, bcntD, bcntS,
                                          row_ptr, esrc, srcn, dstn);
    gather1_kernel<<<(NN * 64 + 255) / 256, 256, 0, stream>>>(row_ptr, esrc, xh,
                                                              srcn, aggb);
    gemm12_kernel<<<(NN + 63) / 64, 256, 0, stream>>>(aggb, w1t, w2t, b1, dstn,
                                                      srcn, hwb);
    gather2_kernel<<<(NN * 64 + 255) / 256, 256, 0, stream>>>(row_ptr, esrc, hwb,
                                                              dstn, b2, out);
}

// Round 2
// 318.704 us; speedup vs baseline: 1.0682x; 1.0071x over previous
//
#include <hip/hip_runtime.h>

// GCN: 2-layer GraphConv, N=100000, E=1600000, 128 -> 128 -> 40 (fp32).
// Round 11: fused gather1+GEMM12.
//   fused_kernel: each of 4 waves gathers its own 16 nodes (24-edge predicated
//     batches, 6 rows in flight) into a wave-private LDS tile, then runs
//     MFMA GEMM1 (relu epilogue) + GEMM2 directly. Weight fragments are read
//     from global (w1t 32KB is L1-resident); LDS ~17KB -> high occupancy for
//     the BW-bound gather phase. Kills the 51 MB aggb round-trip + 1 launch.
//   gather2: unchanged (18-edge predicated batches).
// CSR build (histconv/partition/pass2) unchanged from Round 9.
constexpr int NN   = 100000;
constexpr int NE   = 1600000;
constexpr int INF  = 128;
constexpr int NC   = 40;

constexpr int BKSH = 9;                        // 512 nodes per coarse bucket
constexpr int NBK  = (NN + 511) / 512;         // 196 buckets
constexpr int EPB  = 4096;                     // edges per partition block
constexpr int PBLK = (NE + EPB - 1) / EPB;     // 391
constexpr int CAP  = 14336;                    // pass2 LDS esrc capacity (56 KB)
constexpr int HB   = 391;                      // hist blocks in merged kernel

typedef __attribute__((ext_vector_type(8))) short short8;
typedef __attribute__((ext_vector_type(4))) float f32x4;

__device__ __forceinline__ float bflo(unsigned int u) { return __uint_as_float(u << 16); }
__device__ __forceinline__ float bfhi(unsigned int u) { return __uint_as_float(u & 0xffff0000u); }
__device__ __forceinline__ unsigned short f2bf(float f) {          // RNE
    unsigned int u = __float_as_uint(f);
    return (unsigned short)((u + 0x7fffu + ((u >> 16) & 1u)) >> 16);
}
__device__ __forceinline__ unsigned int pack2(float a, float b) {
    return (unsigned int)f2bf(a) | ((unsigned int)f2bf(b) << 16);
}

// blocks 0..HB-1: coarse dst-bucket AND src-bucket histograms (LDS aggregated).
// blocks HB..HB+6249: x (fp32) -> xh (bf16). +2 blocks: W1/W2 transpose->bf16.
__global__ __launch_bounds__(256) void histconv_kernel(const int* __restrict__ src,
                                                       const int* __restrict__ dst,
                                                       unsigned int* __restrict__ bcntD,
                                                       unsigned int* __restrict__ bcntS,
                                                       const float* __restrict__ x,
                                                       const float* __restrict__ W1,
                                                       const float* __restrict__ W2,
                                                       unsigned short* __restrict__ xh,
                                                       unsigned short* __restrict__ w1t,
                                                       unsigned short* __restrict__ w2t) {
    const int b = blockIdx.x;
    const int tid = threadIdx.x;
    if (b < HB) {
        __shared__ unsigned int hcD[NBK];
        __shared__ unsigned int hcS[NBK];
        for (int i = tid; i < NBK; i += 256) { hcD[i] = 0u; hcS[i] = 0u; }
        __syncthreads();
        int gid = b * 256 + tid;
        int stride = HB * 256;
        for (int e = gid; e < NE; e += stride) {
            atomicAdd(&hcD[dst[e] >> BKSH], 1u);
            atomicAdd(&hcS[src[e] >> BKSH], 1u);
        }
        __syncthreads();
        for (int i = tid; i < NBK; i += 256) {
            if (hcD[i]) atomicAdd(&bcntD[i], hcD[i]);
            if (hcS[i]) atomicAdd(&bcntS[i], hcS[i]);
        }
    } else if (b < HB + 6250) {
        int j = (b - HB) * 256 + tid;                // uint4 index, N*128/8 = 1.6M
        float4 v0 = ((const float4*)x)[2 * j];
        float4 v1 = ((const float4*)x)[2 * j + 1];
        uint4 o;
        o.x = pack2(v0.x, v0.y);
        o.y = pack2(v0.z, v0.w);
        o.z = pack2(v1.x, v1.y);
        o.w = pack2(v1.z, v1.w);
        ((uint4*)xh)[j] = o;
    } else if (b == HB + 6250) {
        for (int i = tid; i < 128 * 128; i += 256) {
            int k = i >> 7, n = i & 127;
            w1t[n * 128 + k] = f2bf(W1[i]);
        }
    } else {
        for (int i = tid; i < 48 * 128; i += 256) {
            int n = i >> 7, k = i & 127;
            w2t[i] = f2bf((n < NC) ? W2[k * NC + n] : 0.f);
        }
    }
}

// dual partition: dst-records (src | dst_local<<17) into epartsD, src-records
// (ushort src_local) into epartsS. Both LDS-staged -> coalesced run dumps.
__global__ __launch_bounds__(256) void partition_kernel(const int* __restrict__ src,
                                                        const int* __restrict__ dst,
                                                        const unsigned int* __restrict__ bcntD,
                                                        const unsigned int* __restrict__ bcntS,
                                                        int* __restrict__ curD_g,
                                                        int* __restrict__ curS_g,
                                                        int* __restrict__ epartsD,
                                                        unsigned short* __restrict__ epartsS) {
    __shared__ int sc[256];
    __shared__ int cntD[NBK], gadjD[NBK], curD[NBK];
    __shared__ int cntS[NBK], gadjS[NBK], curS[NBK];
    __shared__ int baselD[NBK], baselS[NBK];
    __shared__ int stageD[EPB];
    __shared__ unsigned short stageS[EPB];
    __shared__ unsigned char bidD[EPB];
    __shared__ unsigned char bidS[EPB];
    const int tid = threadIdx.x;
    const int e0 = blockIdx.x * EPB;
    const int total = min(EPB, NE - e0);

    // self-scan of global bucket counts -> base offsets (dst then src)
    {
        int v = (tid < NBK) ? (int)bcntD[tid] : 0;
        sc[tid] = v;
        __syncthreads();
        for (int off = 1; off < 256; off <<= 1) {
            int t = (tid >= off) ? sc[tid - off] : 0;
            __syncthreads();
            sc[tid] += t;
            __syncthreads();
        }
        if (tid < NBK) baselD[tid] = sc[tid] - v;
        __syncthreads();
        v = (tid < NBK) ? (int)bcntS[tid] : 0;
        sc[tid] = v;
        __syncthreads();
        for (int off = 1; off < 256; off <<= 1) {
            int t = (tid >= off) ? sc[tid - off] : 0;
            __syncthreads();
            sc[tid] += t;
            __syncthreads();
        }
        if (tid < NBK) baselS[tid] = sc[tid] - v;
    }
    for (int i = tid; i < NBK; i += 256) { cntD[i] = 0; cntS[i] = 0; }
    __syncthreads();
    // phase A: count per bucket (both keys)
    for (int i = tid; i < total; i += 256) {
        atomicAdd(&cntD[dst[e0 + i] >> BKSH], 1);
        atomicAdd(&cntS[src[e0 + i] >> BKSH], 1);
    }
    __syncthreads();
    // exclusive scans of cntD, cntS; reserve global ranges
    {
        int v = (tid < NBK) ? cntD[tid] : 0;
        sc[tid] = v;
        __syncthreads();
        for (int off = 1; off < 256; off <<= 1) {
            int t = (tid >= off) ? sc[tid - off] : 0;
            __syncthreads();
            sc[tid] += t;
            __syncthreads();
        }
        if (tid < NBK) {
            int excl = sc[tid] - v;
            curD[tid] = excl;
            int g = (v > 0) ? atomicAdd(&curD_g[tid], v) : 0;   // zero-based
            gadjD[tid] = baselD[tid] + g - excl;
        }
        __syncthreads();
        v = (tid < NBK) ? cntS[tid] : 0;
        sc[tid] = v;
        __syncthreads();
        for (int off = 1; off < 256; off <<= 1) {
            int t = (tid >= off) ? sc[tid - off] : 0;
            __syncthreads();
            sc[tid] += t;
            __syncthreads();
        }
        if (tid < NBK) {
            int excl = sc[tid] - v;
            curS[tid] = excl;
            int g = (v > 0) ? atomicAdd(&curS_g[tid], v) : 0;
            gadjS[tid] = baselS[tid] + g - excl;
        }
    }
    __syncthreads();
    // phase B: re-read edges, stage grouped by bucket (both keys)
    for (int i = tid; i < total; i += 256) {
        int s = src[e0 + i];
        int d = dst[e0 + i];
        int bD = d >> BKSH;
        int offD = atomicAdd(&curD[bD], 1);
        stageD[offD] = s | ((d - (bD << BKSH)) << 17);
        bidD[offD] = (unsigned char)bD;
        int bS = s >> BKSH;
        int offS = atomicAdd(&curS[bS], 1);
        stageS[offS] = (unsigned short)(s - (bS << BKSH));
        bidS[offS] = (unsigned char)bS;
    }
    __syncthreads();
    // dumps: consecutive j within a bucket-run -> consecutive global addresses
    for (int j = tid; j < total; j += 256) {
        int b = bidD[j];
        epartsD[gadjD[b] + j] = stageD[j];
    }
    for (int j = tid; j < total; j += 256) {
        int b = bidS[j];
        epartsS[gadjS[b] + j] = stageS[j];
    }
}

// per-bucket: dst CSR (hist+scan+LDS scatter -> row_ptr, dstn, esrc) AND
// src out-degree hist -> srcn. All histograms in LDS.
__global__ __launch_bounds__(512) void pass2_kernel(const int* __restrict__ epartsD,
                                                    const unsigned short* __restrict__ epartsS,
                                                    const unsigned int* __restrict__ bcntD,
                                                    const unsigned int* __restrict__ bcntS,
                                                    int* __restrict__ row_ptr,
                                                    int* __restrict__ esrc,
                                                    float* __restrict__ srcn,
                                                    float* __restrict__ dstn) {
    __shared__ int hist[512];
    __shared__ int cur[512];
    __shared__ int histS[512];
    __shared__ int lesrc[CAP];
    __shared__ int base_s, cnt_s, baseS_s, cntS_s;
    const int tid = threadIdx.x;
    const int b = blockIdx.x;

    // self-scans of bucket counts -> this bucket's base/cnt (dst, then src)
    {
        int v = (tid < NBK) ? (int)bcntD[tid] : 0;
        hist[tid] = v;
        __syncthreads();
        for (int off = 1; off < 512; off <<= 1) {
            int t = (tid >= off) ? hist[tid - off] : 0;
            __syncthreads();
            hist[tid] += t;
            __syncthreads();
        }
        if (tid == b) { base_s = hist[b] - v; cnt_s = v; }
        __syncthreads();
        v = (tid < NBK) ? (int)bcntS[tid] : 0;
        hist[tid] = v;
        __syncthreads();
        for (int off = 1; off < 512; off <<= 1) {
            int t = (tid >= off) ? hist[tid - off] : 0;
            __syncthreads();
            hist[tid] += t;
            __syncthreads();
        }
        if (tid == b) { baseS_s = hist[b] - v; cntS_s = v; }
        __syncthreads();
    }
    const int base = base_s;
    const int cnt = cnt_s;
    const int baseS = baseS_s;
    const int cntS = cntS_s;
    const int n0 = b << BKSH;
    const int nloc = min(512, NN - n0);

    hist[tid] = 0;
    histS[tid] = 0;
    __syncthreads();
    for (int j = tid; j < cnt; j += 512)
        atomicAdd(&hist[epartsD[base + j] >> 17], 1);
    for (int j = tid; j < cntS; j += 512)
        atomicAdd(&histS[(int)epartsS[baseS + j]], 1);
    __syncthreads();
    int myc = hist[tid];
    int mycS = histS[tid];
    for (int off = 1; off < 512; off <<= 1) {
        int t = (tid >= off) ? hist[tid - off] : 0;
        __syncthreads();
        hist[tid] += t;
        __syncthreads();
    }
    int excl = hist[tid] - myc;
    cur[tid] = excl;
    if (tid < nloc) {
        int g = n0 + tid;
        row_ptr[g] = base + excl;
        dstn[g] = rsqrtf(fmaxf((float)myc, 1.0f));    // dst_norm (in-degree)
        srcn[g] = rsqrtf(fmaxf((float)mycS, 1.0f));   // src_norm (out-degree)
    }
    if (b == NBK - 1 && tid == 0) row_ptr[NN] = NE;
    __syncthreads();
    if (cnt <= CAP) {
        for (int j = tid; j < cnt; j += 512) {
            int rec = epartsD[base + j];
            int pos = atomicAdd(&cur[rec >> 17], 1);
            lesrc[pos] = rec & 0x1FFFF;
        }
        __syncthreads();
        for (int j = tid; j < cnt; j += 512) esrc[base + j] = lesrc[j];
    } else {
        for (int j = tid; j < cnt; j += 512) {
            int rec = epartsD[base + j];
            int pos = atomicAdd(&cur[rec >> 17], 1);
            esrc[base + pos] = rec & 0x1FFFF;
        }
    }
}

// Fused gather1 + GEMM1 + GEMM2. 64 nodes/block, 4 waves, wave-private 16 rows.
// Phase 1: per wave, 16 nodes sequentially; predicated 24-edge batches
//   (quad group owns edge slot t*4+quad, l16 reads uint4 of the 256 B row);
//   shfl-reduce over quads; lanes<16 write the bf16 row into the wave's own
//   At rows (no cross-wave LDS traffic -> single barrier for dn/sn/b1 only).
// Phase 2: MFMA 16x16x32 bf16. A-frags from At (own rows); B-frags straight
//   from global w1t/w2t (L1-resident, shared across all blocks). h = relu(
//   dstn*(agg@W1)+b1) -> back into At; out = (h@W2)*srcn -> hwb (bf16, 40c).
__global__ __launch_bounds__(256) void fused_kernel(const int* __restrict__ row_ptr,
                                                    const int* __restrict__ esrc,
                                                    const unsigned short* __restrict__ xh,
                                                    const float* __restrict__ srcn,
                                                    const unsigned short* __restrict__ w1t,
                                                    const unsigned short* __restrict__ w2t,
                                                    const float* __restrict__ b1,
                                                    const float* __restrict__ dstn,
                                                    unsigned short* __restrict__ hwb) {
    __shared__ unsigned short At[64 * 128];    // 16 KB: agg tile, then h tile
    __shared__ float dn[64], sn[64], b1l[128];
    const int tid  = threadIdx.x;
    const int r0   = blockIdx.x * 64;
    const int wv   = tid >> 6;
    const int lane = tid & 63;

    if (tid < 64) {
        int r = r0 + tid;
        dn[tid] = (r < NN) ? dstn[r] : 0.f;
        sn[tid] = (r < NN) ? srcn[r] : 0.f;
    }
    if (tid >= 64 && tid < 192) b1l[tid - 64] = b1[tid - 64];
    __syncthreads();

    // ---- phase 1: gather 16 nodes into wave-private At rows ----
    const int quad = lane >> 4;       // edge-slot group 0..3
    const int l16  = lane & 15;       // uint4 index within 256 B row
    for (int i = 0; i < 16; ++i) {
        const int node = r0 + wv * 16 + i;
        float a0 = 0.f, a1 = 0.f, a2 = 0.f, a3 = 0.f;
        float a4 = 0.f, a5 = 0.f, a6 = 0.f, a7 = 0.f;
        if (node < NN) {
            int beg = __builtin_amdgcn_readfirstlane(row_ptr[node]);
            int end = __builtin_amdgcn_readfirstlane(row_ptr[node + 1]);
            for (int e = beg; e < end; e += 24) {
                const int rem = end - e;
                int s[6];
#pragma unroll
                for (int t = 0; t < 6; ++t) {
                    int slot = t * 4 + quad;
                    s[t] = esrc[(slot < rem) ? (e + slot) : beg];
                }
                float n[6];
                uint4 u[6];
#pragma unroll
                for (int t = 0; t < 6; ++t) {
                    int slot = t * 4 + quad;
                    n[t] = (slot < rem) ? srcn[s[t]] : 0.f;
                    u[t] = ((const uint4*)(xh + (size_t)s[t] * INF))[l16];
                }
#pragma unroll
                for (int t = 0; t < 6; ++t) {
                    a0 += bflo(u[t].x) * n[t];
                    a1 += bfhi(u[t].x) * n[t];
                    a2 += bflo(u[t].y) * n[t];
                    a3 += bfhi(u[t].y) * n[t];
                    a4 += bflo(u[t].z) * n[t];
                    a5 += bfhi(u[t].z) * n[t];
                    a6 += bflo(u[t].w) * n[t];
                    a7 += bfhi(u[t].w) * n[t];
                }
            }
        }
        a0 += __shfl_down(a0, 32); a1 += __shfl_down(a1, 32);
        a2 += __shfl_down(a2, 32); a3 += __shfl_down(a3, 32);
        a4 += __shfl_down(a4, 32); a5 += __shfl_down(a5, 32);
        a6 += __shfl_down(a6, 32); a7 += __shfl_down(a7, 32);
        a0 += __shfl_down(a0, 16); a1 += __shfl_down(a1, 16);
        a2 += __shfl_down(a2, 16); a3 += __shfl_down(a3, 16);
        a4 += __shfl_down(a4, 16); a5 += __shfl_down(a5, 16);
        a6 += __shfl_down(a6, 16); a7 += __shfl_down(a7, 16);
        if (lane < 16) {
            uint4 o;
            o.x = pack2(a0, a1);
            o.y = pack2(a2, a3);
            o.z = pack2(a4, a5);
            o.w = pack2(a6, a7);
            *(uint4*)&At[(wv * 16 + i) * 128 + l16 * 8] = o;
        }
    }
    // no barrier: each wave reads only its own 16 rows below

    // ---- phase 2: MFMA GEMM1 (+relu) and GEMM2 ----
    const int lrow  = lane & 15;
    const int lquad = lane >> 4;

    short8 afrag[4];
#pragma unroll
    for (int ks = 0; ks < 4; ++ks)
        afrag[ks] = *(const short8*)&At[(wv * 16 + lrow) * 128 + ks * 32 + lquad * 8];
    float hreg[8][4];
#pragma unroll
    for (int nt = 0; nt < 8; ++nt) {
        f32x4 acc = {0.f, 0.f, 0.f, 0.f};
#pragma unroll
        for (int ks = 0; ks < 4; ++ks) {
            short8 bfr = *(const short8*)&w1t[(nt * 16 + lrow) * 128 + ks * 32 + lquad * 8];
            acc = __builtin_amdgcn_mfma_f32_16x16x32_bf16(afrag[ks], bfr, acc, 0, 0, 0);
        }
#pragma unroll
        for (int i = 0; i < 4; ++i) hreg[nt][i] = acc[i];
    }
#pragma unroll
    for (int nt = 0; nt < 8; ++nt) {
        int col = nt * 16 + lrow;
        float bb = b1l[col];
#pragma unroll
        for (int i = 0; i < 4; ++i) {
            int row = wv * 16 + lquad * 4 + i;
            At[row * 128 + col] = f2bf(fmaxf(hreg[nt][i] * dn[row] + bb, 0.f));
        }
    }
    // still wave-private (each wave reads back only its own rows)

#pragma unroll
    for (int ks = 0; ks < 4; ++ks)
        afrag[ks] = *(const short8*)&At[(wv * 16 + lrow) * 128 + ks * 32 + lquad * 8];
#pragma unroll
    for (int nt = 0; nt < 3; ++nt) {
        f32x4 acc = {0.f, 0.f, 0.f, 0.f};
#pragma unroll
        for (int ks = 0; ks < 4; ++ks) {
            short8 bfr = *(const short8*)&w2t[(nt * 16 + lrow) * 128 + ks * 32 + lquad * 8];
            acc = __builtin_amdgcn_mfma_f32_16x16x32_bf16(afrag[ks], bfr, acc, 0, 0, 0);
        }
        int col = nt * 16 + lrow;
        if (col < NC) {
#pragma unroll
            for (int i = 0; i < 4; ++i) {
                int row = wv * 16 + lquad * 4 + i;
                int grow = r0 + row;
                if (grow < NN)
                    hwb[(size_t)grow * NC + col] = f2bf(acc[i] * sn[row]);
            }
        }
    }
}

// one wave per node. lane = g*10+j (g<6, j<10): 6 edge slots, each edge's
// 80 B row read by 10 lanes as uint2 (4 bf16). Predicated 18-edge batches
// (3 independent loads per lane in flight); invalid slots clamp to edge `beg`
// with multiplicative zero mask. fp32 acc; shfl reduce into lanes 0..9,
// which store float4 with fused *dstn + b2.
__global__ __launch_bounds__(256) void gather2_kernel(const int* __restrict__ row_ptr,
                                                      const int* __restrict__ esrc,
                                                      const unsigned short* __restrict__ hwb,
                                                      const float* __restrict__ dst_norm,
                                                      const float* __restrict__ b2,
                                                      float* __restrict__ out) {
    int node = (blockIdx.x * blockDim.x + threadIdx.x) >> 6;
    int lane = threadIdx.x & 63;
    if (node >= NN) return;
    int beg = __builtin_amdgcn_readfirstlane(row_ptr[node]);
    int end = __builtin_amdgcn_readfirstlane(row_ptr[node + 1]);
    const int g = lane / 10;          // edge slot 0..5 (g==6: lanes 60-63 masked)
    const int j = lane - g * 10;      // uint2 index within 80 B row
    const bool active = (g < 6);
    float4 acc = make_float4(0.f, 0.f, 0.f, 0.f);
    for (int e = beg; e < end; e += 18) {
        const int rem = end - e;
        int s[3];
        float m[3];
#pragma unroll
        for (int q = 0; q < 3; ++q) {
            int slot = q * 6 + g;
            bool v = active && (slot < rem);
            int idx = v ? (e + slot) : beg;
            s[q] = esrc[idx];
            m[q] = v ? 1.f : 0.f;
        }
        uint2 u[3];
#pragma unroll
        for (int q = 0; q < 3; ++q)
            u[q] = ((const uint2*)(hwb + (size_t)s[q] * NC))[j];
#pragma unroll
        for (int q = 0; q < 3; ++q) {
            acc.x += bflo(u[q].x) * m[q];
            acc.y += bfhi(u[q].x) * m[q];
            acc.z += bflo(u[q].y) * m[q];
            acc.w += bfhi(u[q].y) * m[q];
        }
    }
    float4 tot = acc;
#pragma unroll
    for (int k = 1; k < 6; ++k) {
        tot.x += __shfl(acc.x, j + 10 * k);
        tot.y += __shfl(acc.y, j + 10 * k);
        tot.z += __shfl(acc.z, j + 10 * k);
        tot.w += __shfl(acc.w, j + 10 * k);
    }
    if (lane < 10) {
        float dnv = dst_norm[node];
        float4 bb = ((const float4*)b2)[j];
        float4 o;
        o.x = tot.x * dnv + bb.x;
        o.y = tot.y * dnv + bb.y;
        o.z = tot.z * dnv + bb.z;
        o.w = tot.w * dnv + bb.w;
        ((float4*)(out + (size_t)node * NC))[j] = o;
    }
}

extern "C" void kernel_launch(void* const* d_in, const int* in_sizes, int n_in,
                              void* d_out, int out_size, void* d_ws, size_t ws_size,
                              hipStream_t stream) {
    const float* x   = (const float*)d_in[0];
    const float* W1  = (const float*)d_in[1];
    const float* b1  = (const float*)d_in[2];
    const float* W2  = (const float*)d_in[3];
    const float* b2  = (const float*)d_in[4];
    const int*   src = (const int*)d_in[5];
    const int*   dst = (const int*)d_in[6];
    float* out = (float*)d_out;

    // workspace (4B units):
    // srcn[NN] | bcntD[256] | bcntS[256] | curD[256] | curS[256] | row_ptr[NN+1] |
    // dstn[NN] | esrc[NE] | pad | xh[NN*64] | w1t[8192] | w2t[3072] | hwb[NN*20]
    float* srcn = (float*)d_ws;
    unsigned int* bcntD = (unsigned int*)(srcn + NN);
    unsigned int* bcntS = bcntD + 256;
    int* curD = (int*)(bcntS + 256);
    int* curS = curD + 256;
    int* row_ptr = curS + 256;
    float* dstn  = (float*)(row_ptr + NN + 1);
    int* esrc    = (int*)(dstn + NN);
    size_t ofs = (size_t)NN + 1024 + (NN + 1) + NN + NE;
    ofs = (ofs + 3) & ~(size_t)3;                 // 16B align
    unsigned short* xh   = (unsigned short*)((float*)d_ws + ofs);
    unsigned short* w1t  = xh + (size_t)NN * INF;
    unsigned short* w2t  = w1t + 128 * 128;
    unsigned short* hwb  = w2t + 48 * 128;

    // edge-record scratch lives in d_out (9.6 MB of 16 MB) — dead before gather2 writes
    int* epartsD = (int*)d_out;                            // 6.4 MB
    unsigned short* epartsS = (unsigned short*)(epartsD + NE);  // 3.2 MB

    hipMemsetAsync(bcntD, 0, 1024 * sizeof(int), stream);  // bcntD|bcntS|curD|curS

    histconv_kernel<<<HB + 6252, 256, 0, stream>>>(src, dst, bcntD, bcntS,
                                                   x, W1, W2, xh, w1t, w2t);
    partition_kernel<<<PBLK, 256, 0, stream>>>(src, dst, bcntD, bcntS, curD, curS,
                                               epartsD, epartsS);
    pass2_kernel<<<NBK, 512, 0, stream>>>(epartsD, epartsS, bcntD, bcntS,
                                          row_ptr, esrc, srcn, dstn);
    fused_kernel<<<(NN + 63) / 64, 256, 0, stream>>>(row_ptr, esrc, xh, srcn,
                                                     w1t, w2t, b1, dstn, hwb);
    gather2_kernel<<<(NN * 64 + 255) / 256, 256, 0, stream>>>(row_ptr, esrc, hwb,
                                                              dstn, b2, out);
}